// Round 7
// baseline (198.659 us; speedup 1.0000x reference)
//
#include <hip/hip_runtime.h>
#include <math.h>

#define NGRAPH 256
#define LNODE  64
#define HEADS  8
#define DIN    512
#define EPG    256   // edges per graph
#define NEDGE  65536

typedef short bf16x8 __attribute__((ext_vector_type(8)));
typedef float f32x4 __attribute__((ext_vector_type(4)));

__device__ __forceinline__ float softplusf(float v) {
    return (v > 20.f) ? v : log1pf(expf(v));
}
__device__ __forceinline__ unsigned short f2bf(float f) {   // RNE f32 -> bf16
    union { float f; unsigned u; } c; c.f = f;
    unsigned r = c.u + 0x7fffu + ((c.u >> 16) & 1u);
    return (unsigned short)(r >> 16);
}
__device__ __forceinline__ float bf2f(unsigned short h) {
    union { float f; unsigned u; } c; c.u = ((unsigned)h) << 16;
    return c.f;
}

// ---------------- K1: CB partials. tposed=0 -> CBp[s][b][i][t] ; tposed=1 -> [s][b][t][i]
__global__ __launch_bounds__(256) void cb_kernel(const float* __restrict__ Bm,
                                                 const float* __restrict__ Cm,
                                                 float* __restrict__ CBp,
                                                 int dper, int tposed) {
    int b = blockIdx.x;
    int slice = blockIdx.y;
    __shared__ float Cs[64 * 68];
    __shared__ float Bs[64 * 68];
    int tid = threadIdx.x;
    int ti = tid >> 4, tj = tid & 15;
    float acc[4][4] = {};
    const float* Cg = Cm + (size_t)b * 64 * DIN;
    const float* Bg = Bm + (size_t)b * 64 * DIN;
    int d_lo = slice * dper;
    for (int d0 = d_lo; d0 < d_lo + dper; d0 += 64) {
        __syncthreads();
        #pragma unroll
        for (int k = 0; k < 4; ++k) {
            int f = k * 256 + tid;
            int row = f >> 4;
            int c4 = (f & 15) << 2;
            *(float4*)(Cs + row * 68 + c4) = *(const float4*)(Cg + row * DIN + d0 + c4);
            *(float4*)(Bs + row * 68 + c4) = *(const float4*)(Bg + row * DIN + d0 + c4);
        }
        __syncthreads();
        for (int d = 0; d < 64; d += 4) {
            float4 cr[4], br[4];
            #pragma unroll
            for (int r = 0; r < 4; ++r) cr[r] = *(const float4*)(Cs + (4 * ti + r) * 68 + d);
            #pragma unroll
            for (int c = 0; c < 4; ++c) br[c] = *(const float4*)(Bs + (4 * tj + c) * 68 + d);
            #pragma unroll
            for (int r = 0; r < 4; ++r)
                #pragma unroll
                for (int c = 0; c < 4; ++c)
                    acc[r][c] += cr[r].x * br[c].x + cr[r].y * br[c].y +
                                 cr[r].z * br[c].z + cr[r].w * br[c].w;
        }
    }
    float* outp = CBp + ((size_t)slice * NGRAPH + b) * 4096;
    if (!tposed) {
        #pragma unroll
        for (int r = 0; r < 4; ++r)
            *(float4*)(outp + (4 * ti + r) * 64 + 4 * tj) =
                make_float4(acc[r][0], acc[r][1], acc[r][2], acc[r][3]);
    } else {
        #pragma unroll
        for (int r = 0; r < 4; ++r)
            #pragma unroll
            for (int c = 0; c < 4; ++c)
                outp[(4 * tj + c) * 64 + (4 * ti + r)] = acc[r][c];
    }
}

// ---------------- K2: fused solve + MFMA GEMM. One block per (graph, head). ----------------
// Wave roles phase 1: w0 stages CB(bf16); w1-3 stage Xt (stride-66, conflict-free
// column-lane writes) + init arrays. Phase 4: w0 solves while all waves preload B-frags.
__global__ __launch_bounds__(256, 5) void fused2_kernel(const float* __restrict__ x,
                                                        const float* __restrict__ dt,
                                                        const float* __restrict__ dt_edge,
                                                        const float* __restrict__ dt_bias,
                                                        const float* __restrict__ Dp,
                                                        const float* __restrict__ dag_masks,
                                                        const int* __restrict__ edge_index,
                                                        const float* __restrict__ CBp,
                                                        float* __restrict__ out,
                                                        int nslice) {
    int b = blockIdx.x;
    int head = blockIdx.y;
    __shared__ unsigned short CBsh[64 * 64];  // CB[i][t] bf16, 8 KB
    __shared__ unsigned short Wl[64 * 72];    // W[i][t] bf16, stride 72 (b128-aligned rows)
    __shared__ unsigned short Xt[64 * 66];    // X^T[e][t] bf16, stride 66 (odd words: free writes)
    __shared__ float Ab[512];                 // band: Ab[i*8 + (i-src)], diff in [1,7]
    __shared__ float dnsh[64];
    __shared__ float ecsh[64];
    __shared__ float dts[64];
    __shared__ float dtt[64];
    int tid = threadIdx.x;
    int w = tid >> 6;
    int lane = tid & 63;
    float bias = dt_bias[head];
    const float* xg0 = x + (size_t)b * 64 * DIN + head * 64;

    // --- phase 1: wave-specialized staging ---
    if (w == 0) {
        // CB = sum slices -> bf16 LDS (wave 0 alone: 16 float4 iters)
        for (int it = 0; it < 16; ++it) {
            int s4 = it * 64 + lane;              // float4 slot 0..1023
            float4 v = *(const float4*)(CBp + (size_t)b * 4096 + s4 * 4);
            for (int s = 1; s < nslice; ++s) {
                float4 p = *(const float4*)(CBp + ((size_t)s * NGRAPH + b) * 4096 + s4 * 4);
                v.x += p.x; v.y += p.y; v.z += p.z; v.w += p.w;
            }
            unsigned short* q = &CBsh[s4 * 4];
            q[0] = f2bf(v.x); q[1] = f2bf(v.y); q[2] = f2bf(v.z); q[3] = f2bf(v.w);
        }
    } else {
        // Xt staging: row t, lane = e. Write bank = (e + t/2)%32 -> 2-way, free.
        for (int t = w - 1; t < 64; t += 3) {
            float v = xg0[(size_t)t * DIN + lane];
            Xt[lane * 66 + t] = f2bf(v);
        }
        if (w == 1) {
            int node = b * 64 + lane;
            dts[lane] = softplusf(dt[node * 16 + head * 2 + 0] + bias);
            dtt[lane] = softplusf(dt[node * 16 + head * 2 + 1] + bias);
        } else if (w == 2) {
            #pragma unroll
            for (int k = 0; k < 8; ++k) Ab[k * 64 + lane] = 0.f;
        } else {
            dnsh[lane] = 0.f;
            ecsh[lane] = 0.f;
        }
    }
    __syncthreads();

    // --- phase 2: edge scatter into band ---
    {
        int e = b * EPG + tid;
        int sl = edge_index[e] & 63;
        int dl = edge_index[NEDGE + e] & 63;
        float mk = dag_masks[e];
        float de = softplusf(dt_edge[e * HEADS + head] + bias);
        float dsum = (dts[sl] + dtt[dl] + de) * 0.57735026918962576451f; // 1/sqrt(3)
        float dexp = expf(-dsum);
        atomicAdd(&Ab[dl * 8 + (dl - sl)], dexp * mk);
        atomicAdd(&dnsh[dl], dsum * mk);
        atomicAdd(&ecsh[dl], mk);
    }
    __syncthreads();

    // --- phase 3: normalize band ---
    for (int k = tid; k < 512; k += 256) {
        int i = k >> 3, d = k & 7;
        int src = i - d;
        if (d >= 1 && src >= 0) {
            float den = sqrtf(ecsh[i] * ecsh[src]);
            if (den < 1.f) den = 1.f;
            Ab[k] = Ab[k] / den;
        }
    }
    __syncthreads();

    // --- phase 4: preload B-frags (Xt ready); wave 0 additionally solves ---
    int m = lane & 15;
    int quad = lane >> 4;
    union { bf16x8 v; unsigned u[4]; } bf[4][2];
    #pragma unroll
    for (int eb = 0; eb < 4; ++eb) {
        int n66 = (eb * 16 + m) * 66;
        #pragma unroll
        for (int h = 0; h < 2; ++h) {
            int base = n66 + h * 32 + quad * 8;
            #pragma unroll
            for (int c = 0; c < 4; ++c)
                bf[eb][h].u[c] = *(const unsigned*)(&Xt[base + 2 * c]);
        }
    }
    if (w == 0) {
        // lane j = column j. W[i][j] = M[i][j]*CB[i][j]*dn[i] (+D on diag)
        int j = lane;
        float Dh = Dp[head];
        float mwin[7] = {0.f, 0.f, 0.f, 0.f, 0.f, 0.f, 0.f};
        for (int i = 0; i < 64; ++i) {
            float mi = (j == i) ? 1.f : 0.f;
            #pragma unroll
            for (int s = 0; s < 7; ++s) mi += Ab[i * 8 + s + 1] * mwin[s];
            float wv = mi * bf2f(CBsh[i * 64 + j]) * dnsh[i];
            if (j == i) wv += Dh;
            Wl[i * 72 + j] = f2bf(wv);   // bank = 4i + j/2 -> 2-way, free
            #pragma unroll
            for (int s = 6; s > 0; --s) mwin[s] = mwin[s - 1];
            mwin[0] = mi;
        }
    }
    __syncthreads();

    // --- phase 5: y[i][e] = sum_t W[i][t] X[t][e] via MFMA 16x16x32 bf16 ---
    // A-frag: lane holds A[m=lane&15][k=quad*8+j]; C/D: col=lane&15, row=quad*4+reg.
    {
        bf16x8 a0 = *(const bf16x8*)(&Wl[(16 * w + m) * 72 + quad * 8]);
        bf16x8 a1 = *(const bf16x8*)(&Wl[(16 * w + m) * 72 + 32 + quad * 8]);
        float* og = out + ((size_t)b * 64) * DIN + head * 64;
        #pragma unroll
        for (int eb = 0; eb < 4; ++eb) {
            f32x4 acc = {0.f, 0.f, 0.f, 0.f};
            acc = __builtin_amdgcn_mfma_f32_16x16x32_bf16(a0, bf[eb][0].v, acc, 0, 0, 0);
            acc = __builtin_amdgcn_mfma_f32_16x16x32_bf16(a1, bf[eb][1].v, acc, 0, 0, 0);
            #pragma unroll
            for (int r = 0; r < 4; ++r) {
                int row = 16 * w + quad * 4 + r;
                og[(size_t)row * DIN + eb * 16 + m] = acc[r];
            }
        }
    }
}

// ---------------- Fallback fused kernel (round-3 main) for small workspace ----------------
__global__ __launch_bounds__(256, 4) void fused_kernel(const float* __restrict__ x,
                                                       const float* __restrict__ dt,
                                                       const float* __restrict__ dt_edge,
                                                       const float* __restrict__ dt_bias,
                                                       const float* __restrict__ Dp,
                                                       const float* __restrict__ dag_masks,
                                                       const int* __restrict__ edge_index,
                                                       const float* __restrict__ CBt,
                                                       float* __restrict__ out,
                                                       int nslice) {
    int b = blockIdx.x;
    int head = blockIdx.y;
    __shared__ float Ab[64 * 8];
    __shared__ float Mt[64 * 68];
    __shared__ float Xs[64 * 64];
    __shared__ float dnsh[64];
    __shared__ float ecsh[64];
    __shared__ float dts[64];
    __shared__ float dtt[64];
    int tid = threadIdx.x;

    int t4 = tid >> 2;
    int ib = (tid & 3) << 4;
    float4 cbsum[4];
    #pragma unroll
    for (int g = 0; g < 4; ++g) cbsum[g] = make_float4(0.f, 0.f, 0.f, 0.f);
    for (int s = 0; s < nslice; ++s) {
        const float* p = CBt + ((size_t)s * NGRAPH + b) * 4096 + t4 * 64 + ib;
        #pragma unroll
        for (int g = 0; g < 4; ++g) {
            float4 v = *(const float4*)(p + 4 * g);
            cbsum[g].x += v.x; cbsum[g].y += v.y; cbsum[g].z += v.z; cbsum[g].w += v.w;
        }
    }
    const float* xg0 = x + ((size_t)b * 64) * DIN + head * 64;
    #pragma unroll
    for (int k = 0; k < 4; ++k) {
        int s = k * 256 + tid;
        int row = s >> 4;
        int c4 = (s & 15) << 2;
        *(float4*)(Xs + row * 64 + c4) = *(const float4*)(xg0 + (size_t)row * DIN + c4);
    }
    for (int k = tid; k < 512; k += 256) Ab[k] = 0.f;
    float bias = dt_bias[head];
    if (tid < 64) {
        dnsh[tid] = 0.f;
        ecsh[tid] = 0.f;
        int node = b * 64 + tid;
        dts[tid] = softplusf(dt[node * 16 + head * 2 + 0] + bias);
        dtt[tid] = softplusf(dt[node * 16 + head * 2 + 1] + bias);
    }
    __syncthreads();
    {
        int e = b * EPG + tid;
        int sl = edge_index[e] & 63;
        int dl = edge_index[NEDGE + e] & 63;
        float mk = dag_masks[e];
        float de = softplusf(dt_edge[e * HEADS + head] + bias);
        float dsum = (dts[sl] + dtt[dl] + de) * 0.57735026918962576451f;
        float dexp = expf(-dsum);
        atomicAdd(&Ab[dl * 8 + (dl - sl)], dexp * mk);
        atomicAdd(&dnsh[dl], dsum * mk);
        atomicAdd(&ecsh[dl], mk);
    }
    __syncthreads();
    for (int k = tid; k < 512; k += 256) {
        int i = k >> 3, d = k & 7;
        int src = i - d;
        if (d >= 1 && src >= 0) {
            float den = sqrtf(ecsh[i] * ecsh[src]);
            if (den < 1.f) den = 1.f;
            Ab[k] = Ab[k] / den;
        }
    }
    __syncthreads();
    if (tid < 64) {
        int j = tid;
        float mwin[7] = {0.f, 0.f, 0.f, 0.f, 0.f, 0.f, 0.f};
        for (int i = 0; i < 64; ++i) {
            float mi = (j == i) ? 1.f : 0.f;
            #pragma unroll
            for (int s = 0; s < 7; ++s) mi += Ab[i * 8 + s + 1] * mwin[s];
            Mt[j * 65 + i] = mi;
            #pragma unroll
            for (int s = 6; s > 0; --s) mwin[s] = mwin[s - 1];
            mwin[0] = mi;
        }
    }
    __syncthreads();
    {
        float wv[16];
        #pragma unroll
        for (int g = 0; g < 4; ++g) {
            float4 dn4 = *(const float4*)(dnsh + ib + 4 * g);
            wv[4 * g + 0] = Mt[t4 * 65 + ib + 4 * g + 0] * cbsum[g].x * dn4.x;
            wv[4 * g + 1] = Mt[t4 * 65 + ib + 4 * g + 1] * cbsum[g].y * dn4.y;
            wv[4 * g + 2] = Mt[t4 * 65 + ib + 4 * g + 2] * cbsum[g].z * dn4.z;
            wv[4 * g + 3] = Mt[t4 * 65 + ib + 4 * g + 3] * cbsum[g].w * dn4.w;
        }
        __syncthreads();
        #pragma unroll
        for (int g = 0; g < 4; ++g)
            *(float4*)(Mt + t4 * 68 + ib + 4 * g) =
                make_float4(wv[4 * g + 0], wv[4 * g + 1], wv[4 * g + 2], wv[4 * g + 3]);
    }
    __syncthreads();
    int ti = tid >> 4, tj = tid & 15;
    float acc[4][4] = {};
    #pragma unroll 4
    for (int t = 0; t < 64; ++t) {
        float4 w4 = *(const float4*)(Mt + t * 68 + 4 * ti);
        float4 xv = *(const float4*)(Xs + t * 64 + 4 * tj);
        acc[0][0] += w4.x * xv.x; acc[0][1] += w4.x * xv.y; acc[0][2] += w4.x * xv.z; acc[0][3] += w4.x * xv.w;
        acc[1][0] += w4.y * xv.x; acc[1][1] += w4.y * xv.y; acc[1][2] += w4.y * xv.z; acc[1][3] += w4.y * xv.w;
        acc[2][0] += w4.z * xv.x; acc[2][1] += w4.z * xv.y; acc[2][2] += w4.z * xv.z; acc[2][3] += w4.z * xv.w;
        acc[3][0] += w4.w * xv.x; acc[3][1] += w4.w * xv.y; acc[3][2] += w4.w * xv.z; acc[3][3] += w4.w * xv.w;
    }
    float Dh = Dp[head];
    #pragma unroll
    for (int r = 0; r < 4; ++r) {
        int i = 4 * ti + r;
        float4 xres = *(const float4*)(Xs + i * 64 + 4 * tj);
        float4 v;
        v.x = acc[r][0] + xres.x * Dh;
        v.y = acc[r][1] + xres.y * Dh;
        v.z = acc[r][2] + xres.z * Dh;
        v.w = acc[r][3] + xres.w * Dh;
        *(float4*)(out + ((size_t)(b * 64 + i)) * DIN + head * 64 + 4 * tj) = v;
    }
}

extern "C" void kernel_launch(void* const* d_in, const int* in_sizes, int n_in,
                              void* d_out, int out_size, void* d_ws, size_t ws_size,
                              hipStream_t stream) {
    const float* x        = (const float*)d_in[0];
    const float* Bm       = (const float*)d_in[1];
    const float* Cm       = (const float*)d_in[2];
    const float* dt       = (const float*)d_in[3];
    const float* dt_edge  = (const float*)d_in[4];
    const float* dt_bias  = (const float*)d_in[5];
    const float* Dp       = (const float*)d_in[6];
    const float* dag_mask = (const float*)d_in[7];
    const int*   edge_idx = (const int*)d_in[8];
    float* out = (float*)d_out;

    const size_t CBSLICE = (size_t)NGRAPH * 4096 * 4;   // 4 MiB per slice
    float* CBp = (float*)d_ws;

    if (ws_size >= 2 * CBSLICE) {
        int nslice = 2;
        cb_kernel<<<dim3(NGRAPH, nslice), 256, 0, stream>>>(Bm, Cm, CBp, DIN / nslice, 0);
        fused2_kernel<<<dim3(NGRAPH, HEADS), 256, 0, stream>>>(x, dt, dt_edge, dt_bias, Dp,
                                                               dag_mask, edge_idx, CBp, out, nslice);
    } else {
        int nslice = 1;
        cb_kernel<<<dim3(NGRAPH, nslice), 256, 0, stream>>>(Bm, Cm, CBp, DIN / nslice, 1);
        fused_kernel<<<dim3(NGRAPH, HEADS), 256, 0, stream>>>(x, dt, dt_edge, dt_bias, Dp,
                                                              dag_mask, edge_idx, CBp, out, nslice);
    }
}